// Round 1
// baseline (3132.017 us; speedup 1.0000x reference)
//
#include <hip/hip_runtime.h>
#include <stdint.h>

#define DD 512

// ---------------- CSR build ----------------
__global__ void hist_kernel(const int* __restrict__ rows, int* __restrict__ counts, int E) {
  int i = blockIdx.x * blockDim.x + threadIdx.x;
  if (i < E) atomicAdd(&counts[rows[i]], 1);
}

__global__ __launch_bounds__(1024) void scan_kernel(const int* __restrict__ counts,
                                                    int* __restrict__ offs, int n) {
  __shared__ int sm[1024];
  int t = threadIdx.x;
  int carry = 0;
  if (t == 0) offs[0] = 0;
  for (int base = 0; base < n; base += 1024) {
    int i = base + t;
    int v = (i < n) ? counts[i] : 0;
    sm[t] = v;
    __syncthreads();
    for (int o = 1; o < 1024; o <<= 1) {
      int x = (t >= o) ? sm[t - o] : 0;
      __syncthreads();
      sm[t] += x;
      __syncthreads();
    }
    if (i < n) offs[i + 1] = carry + sm[t];
    carry += sm[1023];
    __syncthreads();
  }
}

__global__ void scatter_kernel(const int* __restrict__ rows, const int* __restrict__ colsIn,
                               const float* __restrict__ valsIn, const int* __restrict__ offs,
                               int* __restrict__ cursor, int* __restrict__ colsC,
                               float* __restrict__ valsC, int E) {
  int i = blockIdx.x * blockDim.x + threadIdx.x;
  if (i < E) {
    int r = rows[i];
    int p = offs[r] + atomicAdd(&cursor[r], 1);
    colsC[p] = colsIn[i];
    valsC[p] = valsIn[i];
  }
}

// ---------------- GEMM: C[M x 512] = A[M x 512] * B[512 x 512] + bias ----------------
// 128x128 tile, 256 threads, 8x8 microtile, K-tile 16.
// A staging uses scalar loads so any lda (513 with +1 offset, 1024) works.
// MODE 0: a0 = acc+bias -> out[r*1024+512+c]; a1 = a0*n[r] -> out[r*1024+c]
// MODE 1: C[r*ldc+c] = acc + bias[c]
template <int MODE>
__global__ __launch_bounds__(256) void gemm_kernel(
    const float* __restrict__ A, int lda,
    const float* __restrict__ B,
    const float* __restrict__ bias,
    float* C, int ldc,
    const float* __restrict__ nvec,
    float* out,
    int M) {
  __shared__ float As[16][128];  // As[k][m]
  __shared__ float Bs[16][128];  // Bs[k][n]
  const int tid = threadIdx.x;
  const int bm = blockIdx.x * 128;
  const int bn = blockIdx.y * 128;
  const int tr = (tid >> 4) << 3;  // 0..120
  const int tc = (tid & 15) << 3;  // 0..120

  float acc[8][8];
#pragma unroll
  for (int i = 0; i < 8; ++i)
#pragma unroll
    for (int j = 0; j < 8; ++j) acc[i][j] = 0.f;

  for (int k0 = 0; k0 < DD; k0 += 16) {
#pragma unroll
    for (int l = 0; l < 2; ++l) {
      int q = tid + l * 256;
      // A: 512 quads = 128 rows x 4 k-quads
      int m = q >> 2, kq = (q & 3) << 2;
      int gm = bm + m;
      float va = 0.f, vb = 0.f, vc = 0.f, vd = 0.f;
      if (gm < M) {
        const float* p = A + (size_t)gm * lda + k0 + kq;
        va = p[0]; vb = p[1]; vc = p[2]; vd = p[3];
      }
      As[kq + 0][m] = va;
      As[kq + 1][m] = vb;
      As[kq + 2][m] = vc;
      As[kq + 3][m] = vd;
      // B: 512 quads = 16 k x 32 n-quads (B rows are aligned/contiguous)
      int kk = q >> 5, nq = (q & 31) << 2;
      *(float4*)&Bs[kk][nq] = *(const float4*)(B + (size_t)(k0 + kk) * DD + bn + nq);
    }
    __syncthreads();
#pragma unroll
    for (int kk = 0; kk < 16; ++kk) {
      float a[8], b[8];
      *(float4*)&a[0] = *(const float4*)&As[kk][tr];
      *(float4*)&a[4] = *(const float4*)&As[kk][tr + 4];
      *(float4*)&b[0] = *(const float4*)&Bs[kk][tc];
      *(float4*)&b[4] = *(const float4*)&Bs[kk][tc + 4];
#pragma unroll
      for (int i = 0; i < 8; ++i)
#pragma unroll
        for (int j = 0; j < 8; ++j) acc[i][j] += a[i] * b[j];
    }
    __syncthreads();
  }

  float bb[8];
  *(float4*)&bb[0] = *(const float4*)&bias[bn + tc];
  *(float4*)&bb[4] = *(const float4*)&bias[bn + tc + 4];

#pragma unroll
  for (int i = 0; i < 8; ++i) {
    int r = bm + tr + i;
    if (r < M) {
      if (MODE == 0) {
        float nv = nvec[r];
#pragma unroll
        for (int jq = 0; jq < 8; jq += 4) {
          float4 a0v;
          a0v.x = acc[i][jq + 0] + bb[jq + 0];
          a0v.y = acc[i][jq + 1] + bb[jq + 1];
          a0v.z = acc[i][jq + 2] + bb[jq + 2];
          a0v.w = acc[i][jq + 3] + bb[jq + 3];
          *(float4*)&out[(size_t)r * 1024 + 512 + bn + tc + jq] = a0v;
          float4 a1v;
          a1v.x = a0v.x * nv; a1v.y = a0v.y * nv; a1v.z = a0v.z * nv; a1v.w = a0v.w * nv;
          *(float4*)&out[(size_t)r * 1024 + bn + tc + jq] = a1v;
        }
      } else {
#pragma unroll
        for (int jq = 0; jq < 8; jq += 4) {
          float4 cv;
          cv.x = acc[i][jq + 0] + bb[jq + 0];
          cv.y = acc[i][jq + 1] + bb[jq + 1];
          cv.z = acc[i][jq + 2] + bb[jq + 2];
          cv.w = acc[i][jq + 3] + bb[jq + 3];
          *(float4*)&C[(size_t)r * ldc + bn + tc + jq] = cv;
        }
      }
    }
  }
}

// ---------------- SpMM: Dst[r] = sum_e vals[e] * H[cols[e]]  (CSR) ----------------
// One block (256 thr) per row; each thread owns 2 of 512 dims (float2).
// MODE 0: Dst[r*ldd+d] = acc
// MODE 1: Dst[r*ldd+d] = a1[r*1024+d] + acc*(1-n[r])   (Dst may alias a1)
template <int MODE>
__global__ __launch_bounds__(256) void spmm_kernel(
    const int* __restrict__ offs, const int* __restrict__ cols,
    const float* __restrict__ vals,
    const float* __restrict__ H,
    float* Dst, int ldd,
    const float* a1, const float* __restrict__ nvec) {
  int r = blockIdx.x;
  int t = threadIdx.x;
  int s = offs[r], e = offs[r + 1];
  int d = t * 2;
  float acc0 = 0.f, acc1 = 0.f;
  int i = s;
  for (; i + 4 <= e; i += 4) {
    int c0 = cols[i], c1 = cols[i + 1], c2 = cols[i + 2], c3 = cols[i + 3];
    float v0 = vals[i], v1 = vals[i + 1], v2 = vals[i + 2], v3 = vals[i + 3];
    float2 h0 = *(const float2*)(H + (size_t)c0 * DD + d);
    float2 h1 = *(const float2*)(H + (size_t)c1 * DD + d);
    float2 h2 = *(const float2*)(H + (size_t)c2 * DD + d);
    float2 h3 = *(const float2*)(H + (size_t)c3 * DD + d);
    acc0 += v0 * h0.x + v1 * h1.x + v2 * h2.x + v3 * h3.x;
    acc1 += v0 * h0.y + v1 * h1.y + v2 * h2.y + v3 * h3.y;
  }
  for (; i < e; ++i) {
    int c = cols[i];
    float v = vals[i];
    float2 h = *(const float2*)(H + (size_t)c * DD + d);
    acc0 += v * h.x;
    acc1 += v * h.y;
  }
  if (MODE == 0) {
    float2 o; o.x = acc0; o.y = acc1;
    *(float2*)(Dst + (size_t)r * ldd + d) = o;
  } else {
    float g = 1.f - nvec[r];
    float2 a = *(const float2*)(a1 + (size_t)r * 1024 + d);
    float2 o; o.x = a.x + acc0 * g; o.y = a.y + acc1 * g;
    *(float2*)(Dst + (size_t)r * ldd + d) = o;
  }
}

extern "C" void kernel_launch(void* const* d_in, const int* in_sizes, int n_in,
                              void* d_out, int out_size, void* d_ws, size_t ws_size,
                              hipStream_t stream) {
  const float* A1       = (const float*)d_in[0];
  const int*   adj_rows = (const int*)d_in[1];
  const int*   adj_cols = (const int*)d_in[2];
  const float* adj_vals = (const float*)d_in[3];
  const float* Lin1     = (const float*)d_in[4];
  const float* Lin1b    = (const float*)d_in[5];
  const float* nvec     = (const float*)d_in[6];
  const float* W1       = (const float*)d_in[7];
  const float* b1       = (const float*)d_in[8];
  const float* W2       = (const float*)d_in[9];
  const float* b2       = (const float*)d_in[10];
  const float* W3       = (const float*)d_in[11];
  const float* b3       = (const float*)d_in[12];
  const int N = in_sizes[6];
  const int E = in_sizes[1];
  float* out = (float*)d_out;

  // workspace layout (256B aligned chunks)
  uint8_t* base = (uint8_t*)d_ws;
  size_t off = 0;
  auto take = [&](size_t bytes) -> void* {
    off = (off + 255) & ~(size_t)255;
    void* r = base + off;
    off += bytes;
    return r;
  };
  float* Y      = (float*)take((size_t)N * DD * sizeof(float));  // dense temp
  int*   colsC  = (int*)take((size_t)E * sizeof(int));
  float* valsC  = (float*)take((size_t)E * sizeof(float));
  int*   offs   = (int*)take((size_t)(N + 1) * sizeof(int));
  int*   counts = (int*)take((size_t)N * sizeof(int));
  int*   cursor = (int*)take((size_t)N * sizeof(int));
  (void)ws_size; (void)n_in; (void)out_size;

  hipMemsetAsync(counts, 0, (size_t)N * sizeof(int), stream);
  hipMemsetAsync(cursor, 0, (size_t)N * sizeof(int), stream);

  // CSR build
  int eb = (E + 255) / 256;
  hist_kernel<<<eb, 256, 0, stream>>>(adj_rows, counts, E);
  scan_kernel<<<1, 1024, 0, stream>>>(counts, offs, N);
  scatter_kernel<<<eb, 256, 0, stream>>>(adj_rows, adj_cols, adj_vals, offs, cursor,
                                         colsC, valsC, E);

  dim3 ggrid((N + 127) / 128, 4);
  // GEMM0: a0 -> out[:,512:], a1 = a0*n -> out[:,0:512] (temp)
  gemm_kernel<0><<<ggrid, 256, 0, stream>>>(A1 + 1, 513, Lin1, Lin1b,
                                            nullptr, 0, nvec, out, N);
  // GEMM1: y1 = x@W1+b1 -> Y
  gemm_kernel<1><<<ggrid, 256, 0, stream>>>(A1 + 1, 513, W1, b1, Y, DD,
                                            nullptr, nullptr, N);
  // SpMM1: x1 = a1 + spmm(y1)*(1-n) -> out[:,0:512]
  spmm_kernel<1><<<N, 256, 0, stream>>>(offs, colsC, valsC, Y, out, 1024, out, nvec);
  // GEMM2: y2 = x1@W2+b2 -> Y   (A = out[:,0:512], lda=1024)
  gemm_kernel<1><<<ggrid, 256, 0, stream>>>(out, 1024, W2, b2, Y, DD,
                                            nullptr, nullptr, N);
  // SpMM2: s2 = spmm(y2) -> out[:,0:512]
  spmm_kernel<0><<<N, 256, 0, stream>>>(offs, colsC, valsC, Y, out, 1024, nullptr, nullptr);
  // GEMM3: y3 = s2@W3+b3 -> Y   (A = out[:,0:512], lda=1024)
  gemm_kernel<1><<<ggrid, 256, 0, stream>>>(out, 1024, W3, b3, Y, DD,
                                            nullptr, nullptr, N);
  // SpMM3: x2 = spmm(y3) -> out[:,0:512]
  spmm_kernel<0><<<N, 256, 0, stream>>>(offs, colsC, valsC, Y, out, 1024, nullptr, nullptr);
}

// Round 2
// 1345.399 us; speedup vs baseline: 2.3279x; 2.3279x over previous
//
#include <hip/hip_runtime.h>
#include <stdint.h>

#define DD 512

typedef __bf16 bf16x8 __attribute__((ext_vector_type(8)));
typedef float f32x4 __attribute__((ext_vector_type(4)));

__device__ __forceinline__ unsigned short f2bf(float f) {
  uint32_t u = __builtin_bit_cast(uint32_t, f);
  u += 0x7fff + ((u >> 16) & 1);  // RNE
  return (unsigned short)(u >> 16);
}
__device__ __forceinline__ float bfbits2f(uint32_t lo16) {
  return __builtin_bit_cast(float, lo16 << 16);
}

// ---------------- CSR build ----------------
__global__ void hist_kernel(const int* __restrict__ rows, int* __restrict__ counts, int E) {
  int i = blockIdx.x * blockDim.x + threadIdx.x;
  if (i < E) atomicAdd(&counts[rows[i]], 1);
}

__global__ __launch_bounds__(256) void scan_block(const int* __restrict__ counts,
                                                  int* __restrict__ offs, int* __restrict__ bsum,
                                                  int n) {
  __shared__ int sm[256];
  int t = threadIdx.x;
  int i = blockIdx.x * 256 + t;
  int v = (i < n) ? counts[i] : 0;
  sm[t] = v;
  __syncthreads();
  for (int o = 1; o < 256; o <<= 1) {
    int x = (t >= o) ? sm[t - o] : 0;
    __syncthreads();
    sm[t] += x;
    __syncthreads();
  }
  if (i < n) offs[i + 1] = sm[t];
  if (t == 255) bsum[blockIdx.x] = sm[255];
}

__global__ __launch_bounds__(256) void scan_tops(int* __restrict__ bsum, int nb) {
  __shared__ int sm[256];
  int t = threadIdx.x;
  int v = (t < nb) ? bsum[t] : 0;
  sm[t] = v;
  __syncthreads();
  for (int o = 1; o < 256; o <<= 1) {
    int x = (t >= o) ? sm[t - o] : 0;
    __syncthreads();
    sm[t] += x;
    __syncthreads();
  }
  if (t < nb) bsum[t] = sm[t];
}

__global__ __launch_bounds__(256) void scan_add(int* __restrict__ offs,
                                                const int* __restrict__ bsum, int n) {
  int i = blockIdx.x * 256 + threadIdx.x;
  int add = (blockIdx.x > 0) ? bsum[blockIdx.x - 1] : 0;
  if (i < n) offs[i + 1] += add;
  if (i == 0) offs[0] = 0;
}

__global__ void scatter_kernel(const int* __restrict__ rows, const int* __restrict__ colsIn,
                               const float* __restrict__ valsIn, const int* __restrict__ offs,
                               int* __restrict__ cursor, int* __restrict__ colsC,
                               unsigned short* __restrict__ valsC, int E) {
  int i = blockIdx.x * blockDim.x + threadIdx.x;
  if (i < E) {
    int r = rows[i];
    int p = offs[r] + atomicAdd(&cursor[r], 1);
    colsC[p] = colsIn[i];
    valsC[p] = f2bf(valsIn[i]);
  }
}

// ---------------- conversions ----------------
// x = A1[:,1:] (lda=513, +1 offset, unaligned) -> Xb bf16 [N][512]
__global__ __launch_bounds__(256) void convert_x(const float* __restrict__ A1,
                                                 __bf16* __restrict__ Xb, int N) {
  int id = blockIdx.x * 256 + threadIdx.x;  // one per 8 elements
  int total = (N * DD) >> 3;
  if (id >= total) return;
  int r = id >> 6;
  int c = (id & 63) * 8;
  const float* p = A1 + (size_t)r * 513 + 1 + c;
  unsigned short h[8];
#pragma unroll
  for (int k = 0; k < 8; ++k) h[k] = f2bf(p[k]);
  uint4 o;
  o.x = (uint32_t)h[0] | ((uint32_t)h[1] << 16);
  o.y = (uint32_t)h[2] | ((uint32_t)h[3] << 16);
  o.z = (uint32_t)h[4] | ((uint32_t)h[5] << 16);
  o.w = (uint32_t)h[6] | ((uint32_t)h[7] << 16);
  *(uint4*)(Xb + (size_t)r * DD + c) = o;
}

// W fp32 [k][n] -> Wt bf16 [n][k]  (transpose + convert)
__global__ __launch_bounds__(256) void convert_wt(const float* __restrict__ W,
                                                  __bf16* __restrict__ Wt) {
  __shared__ float tile[32][33];
  int bx = blockIdx.x * 32;  // n base
  int by = blockIdx.y * 32;  // k base
  int tx = threadIdx.x & 31, ty = threadIdx.x >> 5;  // ty 0..7
#pragma unroll
  for (int q = 0; q < 4; ++q)
    tile[ty + q * 8][tx] = W[(size_t)(by + ty + q * 8) * DD + bx + tx];
  __syncthreads();
  unsigned short* Wts = (unsigned short*)Wt;
#pragma unroll
  for (int q = 0; q < 4; ++q)
    Wts[(size_t)(bx + ty + q * 8) * DD + by + tx] = f2bf(tile[tx][ty + q * 8]);
}

// ---------------- MFMA GEMM: C[M x 512] = A[M x 512] * B + bias ----------------
// A bf16 [M][512]; Bt bf16 [n][k] (transposed weights).
// 128x128 tile, 256 thr = 4 waves (2x2 of 64x64), BK=64, mfma_f32_16x16x32_bf16.
// MODE 0: a0 = acc+bias -> out[r*1024+512+c] (fp32); a1 = a0*n[r] -> out[r*1024+c]
// MODE 1: Yb[r*512+c] = bf16(acc + bias[c])
template <int MODE>
__global__ __launch_bounds__(256) void gemm_mfma(
    const __bf16* __restrict__ A,
    const __bf16* __restrict__ Bt,
    const float* __restrict__ bias,
    __bf16* __restrict__ Yb,
    float* __restrict__ out,
    const float* __restrict__ nvec,
    int M) {
  __shared__ __bf16 As[128][72];  // [m][k], +8 pad keeps 16B align, breaks bank aliasing
  __shared__ __bf16 Bs[128][72];  // [n][k]
  const int tid = threadIdx.x;
  const int bm = blockIdx.x * 128;
  const int bn = blockIdx.y * 128;
  const int lane = tid & 63;
  const int w = tid >> 6;
  const int wm = (w & 1) * 64;
  const int wn = (w >> 1) * 64;
  const int m16 = lane & 15;
  const int quad = lane >> 4;

  f32x4 acc[4][4];
#pragma unroll
  for (int i = 0; i < 4; ++i)
#pragma unroll
    for (int j = 0; j < 4; ++j) acc[i][j] = (f32x4){0.f, 0.f, 0.f, 0.f};

  for (int k0 = 0; k0 < DD; k0 += 64) {
#pragma unroll
    for (int l = 0; l < 4; ++l) {
      int id = tid + l * 256;      // 1024 ids: 128 rows x 8 16B-chunks
      int row = id >> 3;
      int ck = (id & 7) * 8;
      int gm = bm + row;
      if (gm >= M) gm = M - 1;  // clamp (stores guarded)
      *(uint4*)&As[row][ck] = *(const uint4*)(A + (size_t)gm * DD + k0 + ck);
      *(uint4*)&Bs[row][ck] = *(const uint4*)(Bt + (size_t)(bn + row) * DD + k0 + ck);
    }
    __syncthreads();
#pragma unroll
    for (int ks = 0; ks < 2; ++ks) {
      int kb = ks * 32 + quad * 8;
      bf16x8 af[4], bf[4];
#pragma unroll
      for (int i = 0; i < 4; ++i) af[i] = *(const bf16x8*)&As[wm + i * 16 + m16][kb];
#pragma unroll
      for (int j = 0; j < 4; ++j) bf[j] = *(const bf16x8*)&Bs[wn + j * 16 + m16][kb];
#pragma unroll
      for (int i = 0; i < 4; ++i)
#pragma unroll
        for (int j = 0; j < 4; ++j)
          acc[i][j] = __builtin_amdgcn_mfma_f32_16x16x32_bf16(af[i], bf[j], acc[i][j], 0, 0, 0);
    }
    __syncthreads();
  }

  float bv[4];
#pragma unroll
  for (int j = 0; j < 4; ++j) bv[j] = bias[bn + wn + j * 16 + m16];

  unsigned short* Ybs = (unsigned short*)Yb;
#pragma unroll
  for (int i = 0; i < 4; ++i) {
#pragma unroll
    for (int r = 0; r < 4; ++r) {
      int row = bm + wm + i * 16 + quad * 4 + r;
      if (row < M) {
        if (MODE == 0) {
          float nv = nvec[row];
#pragma unroll
          for (int j = 0; j < 4; ++j) {
            int c = bn + wn + j * 16 + m16;
            float a0 = acc[i][j][r] + bv[j];
            out[(size_t)row * 1024 + 512 + c] = a0;
            out[(size_t)row * 1024 + c] = a0 * nv;
          }
        } else {
#pragma unroll
          for (int j = 0; j < 4; ++j) {
            int c = bn + wn + j * 16 + m16;
            Ybs[(size_t)row * DD + c] = f2bf(acc[i][j][r] + bv[j]);
          }
        }
      }
    }
  }
}

// ---------------- SpMM (CSR, bf16 H): row r, 256 thr, 2 dims/thread ----------------
// MODE 0: Xb[r*512+d] = bf16(acc)
// MODE 1: Xb[r*512+d] = bf16(a1[r*1024+d] + acc*(1-n[r]))
// MODE 2: outF[r*1024+d] = acc (fp32)
template <int MODE>
__global__ __launch_bounds__(256) void spmm_bf16(
    const int* __restrict__ offs, const int* __restrict__ cols,
    const unsigned short* __restrict__ vals,
    const __bf16* __restrict__ H,
    __bf16* __restrict__ Xb, float* __restrict__ outF,
    const float* __restrict__ a1, const float* __restrict__ nvec) {
  int r = blockIdx.x;
  int t = threadIdx.x;
  int s = offs[r], e = offs[r + 1];
  int d = t * 2;
  float acc0 = 0.f, acc1 = 0.f;
  int i = s;
  for (; i + 4 <= e; i += 4) {
    int c0 = cols[i], c1 = cols[i + 1], c2 = cols[i + 2], c3 = cols[i + 3];
    float v0 = bfbits2f(vals[i]);
    float v1 = bfbits2f(vals[i + 1]);
    float v2 = bfbits2f(vals[i + 2]);
    float v3 = bfbits2f(vals[i + 3]);
    uint32_t h0 = *(const uint32_t*)(H + (size_t)c0 * DD + d);
    uint32_t h1 = *(const uint32_t*)(H + (size_t)c1 * DD + d);
    uint32_t h2 = *(const uint32_t*)(H + (size_t)c2 * DD + d);
    uint32_t h3 = *(const uint32_t*)(H + (size_t)c3 * DD + d);
    acc0 += v0 * bfbits2f(h0 & 0xffffu) + v1 * bfbits2f(h1 & 0xffffu) +
            v2 * bfbits2f(h2 & 0xffffu) + v3 * bfbits2f(h3 & 0xffffu);
    acc1 += v0 * bfbits2f(h0 >> 16) + v1 * bfbits2f(h1 >> 16) +
            v2 * bfbits2f(h2 >> 16) + v3 * bfbits2f(h3 >> 16);
  }
  for (; i < e; ++i) {
    int c = cols[i];
    float v = bfbits2f(vals[i]);
    uint32_t h = *(const uint32_t*)(H + (size_t)c * DD + d);
    acc0 += v * bfbits2f(h & 0xffffu);
    acc1 += v * bfbits2f(h >> 16);
  }
  if (MODE == 2) {
    float2 o;
    o.x = acc0;
    o.y = acc1;
    *(float2*)(outF + (size_t)r * 1024 + d) = o;
  } else {
    if (MODE == 1) {
      float g = 1.f - nvec[r];
      float2 a = *(const float2*)(a1 + (size_t)r * 1024 + d);
      acc0 = a.x + acc0 * g;
      acc1 = a.y + acc1 * g;
    }
    uint32_t p = ((uint32_t)f2bf(acc1) << 16) | (uint32_t)f2bf(acc0);
    *(uint32_t*)((unsigned short*)Xb + (size_t)r * DD + d) = p;
  }
}

extern "C" void kernel_launch(void* const* d_in, const int* in_sizes, int n_in,
                              void* d_out, int out_size, void* d_ws, size_t ws_size,
                              hipStream_t stream) {
  const float* A1       = (const float*)d_in[0];
  const int*   adj_rows = (const int*)d_in[1];
  const int*   adj_cols = (const int*)d_in[2];
  const float* adj_vals = (const float*)d_in[3];
  const float* Lin1     = (const float*)d_in[4];
  const float* Lin1b    = (const float*)d_in[5];
  const float* nvec     = (const float*)d_in[6];
  const float* W1       = (const float*)d_in[7];
  const float* b1       = (const float*)d_in[8];
  const float* W2       = (const float*)d_in[9];
  const float* b2       = (const float*)d_in[10];
  const float* W3       = (const float*)d_in[11];
  const float* b3       = (const float*)d_in[12];
  const int N = in_sizes[6];
  const int E = in_sizes[1];
  float* out = (float*)d_out;

  uint8_t* base = (uint8_t*)d_ws;
  size_t off = 0;
  auto take = [&](size_t bytes) -> void* {
    off = (off + 255) & ~(size_t)255;
    void* r = base + off;
    off += bytes;
    return r;
  };
  __bf16* Xb     = (__bf16*)take((size_t)N * DD * 2);       // 51.2 MB (x -> x1 -> s2)
  __bf16* Yb     = (__bf16*)take((size_t)N * DD * 2);       // 51.2 MB (GEMM outs)
  __bf16* Wt     = (__bf16*)take((size_t)4 * DD * DD * 2);  // 2 MB (transposed weights)
  int*    colsC  = (int*)take((size_t)E * sizeof(int));
  unsigned short* valsC = (unsigned short*)take((size_t)E * 2);
  int*    offs   = (int*)take((size_t)(N + 1) * sizeof(int));
  int*    counts = (int*)take((size_t)N * sizeof(int));     // reused as cursor
  int*    bsum   = (int*)take(1024);
  (void)ws_size; (void)n_in; (void)out_size;

  __bf16* Wt0 = Wt;
  __bf16* Wt1 = Wt + (size_t)DD * DD;
  __bf16* Wt2 = Wt + (size_t)2 * DD * DD;
  __bf16* Wt3 = Wt + (size_t)3 * DD * DD;

  int eb = (E + 255) / 256;
  int nb = (N + 255) / 256;

  // CSR build
  hipMemsetAsync(counts, 0, (size_t)N * sizeof(int), stream);
  hist_kernel<<<eb, 256, 0, stream>>>(adj_rows, counts, E);
  scan_block<<<nb, 256, 0, stream>>>(counts, offs, bsum, N);
  scan_tops<<<1, 256, 0, stream>>>(bsum, nb);
  scan_add<<<nb, 256, 0, stream>>>(offs, bsum, N);
  hipMemsetAsync(counts, 0, (size_t)N * sizeof(int), stream);  // cursor
  scatter_kernel<<<eb, 256, 0, stream>>>(adj_rows, adj_cols, adj_vals, offs, counts,
                                         colsC, valsC, E);

  // conversions
  convert_x<<<(N * DD / 8 + 255) / 256, 256, 0, stream>>>(A1, Xb, N);
  dim3 wgrid(16, 16);
  convert_wt<<<wgrid, 256, 0, stream>>>(Lin1, Wt0);
  convert_wt<<<wgrid, 256, 0, stream>>>(W1, Wt1);
  convert_wt<<<wgrid, 256, 0, stream>>>(W2, Wt2);
  convert_wt<<<wgrid, 256, 0, stream>>>(W3, Wt3);

  dim3 ggrid((N + 127) / 128, 4);
  // GEMM0: a0 -> out[:,512:] fp32; a1 = a0*n -> out[:,0:512] fp32
  gemm_mfma<0><<<ggrid, 256, 0, stream>>>(Xb, Wt0, Lin1b, nullptr, out, nvec, N);
  // GEMM1: y1 -> Yb
  gemm_mfma<1><<<ggrid, 256, 0, stream>>>(Xb, Wt1, b1, Yb, nullptr, nullptr, N);
  // SpMM1: x1 = a1 + spmm(y1)*(1-n) -> Xb (bf16)
  spmm_bf16<1><<<N, 256, 0, stream>>>(offs, colsC, valsC, Yb, Xb, nullptr, out, nvec);
  // GEMM2: y2 -> Yb
  gemm_mfma<1><<<ggrid, 256, 0, stream>>>(Xb, Wt2, b2, Yb, nullptr, nullptr, N);
  // SpMM2: s2 -> Xb (bf16)
  spmm_bf16<0><<<N, 256, 0, stream>>>(offs, colsC, valsC, Yb, Xb, nullptr, nullptr, nullptr);
  // GEMM3: y3 -> Yb
  gemm_mfma<1><<<ggrid, 256, 0, stream>>>(Xb, Wt3, b3, Yb, nullptr, nullptr, N);
  // SpMM3: x2 -> out[:,0:512] fp32
  spmm_bf16<2><<<N, 256, 0, stream>>>(offs, colsC, valsC, Yb, nullptr, out, nullptr, nullptr);
}